// Round 22
// baseline (230.995 us; speedup 1.0000x reference)
//
#include <hip/hip_runtime.h>
#include <hip/hip_bf16.h>

#define RFL(x) __builtin_amdgcn_readfirstlane(x)

// ---------------- weight transpose: c1wT[k][64], c2wT[k][32]
__global__ void __launch_bounds__(256) wT_k(const float* __restrict__ c1w,
                                            const float* __restrict__ c2w,
                                            float* __restrict__ c1wT,
                                            float* __restrict__ c2wT) {
  int idx = blockIdx.x * 256 + threadIdx.x;
  if (idx < 4800) {
    int o = idx / 75, k = idx % 75;
    c1wT[k * 64 + o] = c1w[idx];
  } else if (idx < 56000) {
    int j = idx - 4800;
    int o = j / 1600, k = j % 1600;
    c2wT[k * 32 + o] = c2w[j];
  }
}

// ---------------- conv1 (R16-best): block = (b, row-pair), 512 thr, 8 waves = (row, o-quarter 16o)
__global__ void __launch_bounds__(512) conv1_k(const float* __restrict__ x,
                                               const float* __restrict__ wT,
                                               const float* __restrict__ bias,
                                               float* __restrict__ out) {
  __shared__ float xt[3][8][456];   // rows iy0..iy0+7, col = ix+2
  int b = blockIdx.x / 75;
  int py2 = blockIdx.x % 75;        // output rows 2*py2, 2*py2+1
  int t = threadIdx.x;
  int iy0 = py2 * 6 - 2;
  if (t < 456) {
    int ix = t - 2;
    bool cok = (ix >= 0) && (ix < 448);
#pragma unroll
    for (int c = 0; c < 3; ++c) {
      const float* xp = x + (size_t)(b * 3 + (2 - c)) * 200704;
#pragma unroll
      for (int r = 0; r < 8; ++r) {
        int iy = iy0 + r;
        bool rok = (iy >= 0) && (iy < 448);
        xt[c][r][t] = (rok && cok) ? xp[(size_t)iy * 448 + ix] : 0.f;
      }
    }
  }
  __syncthreads();
  int lane = t & 63;
  int w = RFL(t >> 6);              // 0..7
  int pl = w >> 2;                  // row-local 0/1
  int ob = (w & 3) * 16;            // o base 0/16/32/48
  int py = py2 * 2 + pl;
  int rbase = pl * 3;
  for (int sub = 0; sub < 3; ++sub) {
    int px = sub * 64 + lane;
    int pxc = min(px, 149);
    float acc[16];
#pragma unroll
    for (int u = 0; u < 16; ++u) acc[u] = 0.f;
    for (int c = 0; c < 3; ++c)
#pragma unroll
      for (int ky = 0; ky < 5; ++ky)
#pragma unroll
        for (int kx = 0; kx < 5; ++kx) {
          float xv = xt[c][rbase + ky][pxc * 3 + kx];
          const float* wr = wT + (c * 25 + ky * 5 + kx) * 64 + ob;  // uniform -> s_load
#pragma unroll
          for (int u = 0; u < 16; ++u) acc[u] += xv * wr[u];
        }
    if (px < 150) {
#pragma unroll
      for (int u = 0; u < 16; ++u)
        out[(size_t)(b * 64 + ob + u) * 22500 + py * 150 + px] =
            fmaxf(acc[u] + bias[ob + u], 0.f);
    }
  }
}

// ---------------- conv2 split-K partial (R16 frozen): block = (b, py-pair, ch), 512 thr,
// 8 waves = (row-local x 4 o-groups of 8 o). LDS 38.9KB.
__global__ void __launch_bounds__(512) conv2p_k(const float* __restrict__ h1,
                                                const float* __restrict__ wT,
                                                float* __restrict__ part2) {
  __shared__ float ht[8][8][152];   // rows iy0..iy0+7
  int blk = blockIdx.x;
  int ch = blk & 7;
  int bpy = blk >> 3;
  int b = bpy / 25;
  int py2 = bpy % 25;               // output rows 2*py2, 2*py2+1
  int t = threadIdx.x;
  int iy0 = py2 * 6 - 2;
  const float* hbase = h1 + (size_t)(b * 64 + ch * 8) * 22500;
  {
    int sub = t >> 7;               // 0..3
    int col = t & 127;
    bool cok = col >= 2;
#pragma unroll
    for (int i = 0; i < 16; ++i) {
      int c = sub * 2 + (i >> 3);   // i>>3 compile-time
      const int r = i & 7;
      int iy = iy0 + r;
      bool ok = (iy >= 0) & (iy < 150) & cok;
      float v = ok ? hbase[c * 22500 + iy * 150 + (col - 2)] : 0.f;
      ht[c][r][col] = v;
    }
#pragma unroll
    for (int it = 0; it < 3; ++it) {
      int e = it * 512 + t;
      int pair = (e * 2731) >> 16;       // e/24
      int col2 = e - pair * 24;
      int c = pair >> 3, r = pair & 7;
      int iy = iy0 + r;
      bool ok = (iy >= 0) & (iy < 150);
      float v = ok ? hbase[c * 22500 + iy * 150 + 126 + col2] : 0.f;
      ht[c][r][128 + col2] = v;
    }
  }
  __syncthreads();
  int lane = t & 63;
  int w = RFL(t >> 6);              // 0..7
  int pl = w >> 2;                  // row-local 0/1
  int ob = (w & 3) * 8;             // o base 0/8/16/24
  int py = py2 * 2 + pl;
  int rbase = pl * 3;
  int pxc = min(lane, 49);
  float acc[8];
#pragma unroll
  for (int u = 0; u < 8; ++u) acc[u] = 0.f;
#pragma unroll
  for (int c = 0; c < 8; ++c)
#pragma unroll
    for (int ky = 0; ky < 5; ++ky)
#pragma unroll
      for (int kx = 0; kx < 5; ++kx) {
        float xv = ht[c][rbase + ky][pxc * 3 + kx];
        const float* wr = wT + ((ch * 8 + c) * 25 + ky * 5 + kx) * 32 + ob;  // s_load
#pragma unroll
        for (int u = 0; u < 8; ++u) acc[u] += xv * wr[u];
      }
  if (lane < 50) {
#pragma unroll
    for (int u = 0; u < 8; ++u)
      part2[((size_t)ch * 256 + b * 32 + ob + u) * 2500 + py * 50 + lane] = acc[u];
  }
}

// ---------------- conv2 combine + gram partial: grid (8,50) = 50 p per block
__global__ void __launch_bounds__(256) comb2g_k(const float* __restrict__ part2,
                                                const float* __restrict__ bias,
                                                float* __restrict__ ft,
                                                float* __restrict__ gramP) {
  __shared__ float tileT[50][36];   // [p-local][o]
  int b = blockIdx.x, pc = blockIdx.y;
  int p0 = pc * 50;
  int t = threadIdx.x;
  for (int e = t; e < 1600; e += 256) {
    int o = e / 50, p = e - o * 50;
    float s = bias[o];
#pragma unroll
    for (int ch = 0; ch < 8; ++ch)
      s += part2[((size_t)ch * 256 + b * 32 + o) * 2500 + p0 + p];
    float v = fmaxf(s, 0.f);
    ft[(size_t)(b * 32 + o) * 2500 + p0 + p] = v;
    tileT[p][o] = v;
  }
  __syncthreads();
  int i = t >> 3, j0 = (t & 7) * 4;
  float4 a = make_float4(0.f, 0.f, 0.f, 0.f);
  for (int p = 0; p < 50; ++p) {
    float ai = tileT[p][i];
    float4 bj = *(const float4*)&tileT[p][j0];
    a.x += ai * bj.x; a.y += ai * bj.y; a.z += ai * bj.z; a.w += ai * bj.w;
  }
  *(float4*)(gramP + ((size_t)(b * 50 + pc)) * 1024 + t * 4) = a;
}

// ---------------- conv2 fallback (monolithic) + gram — used if ws too small
__global__ void __launch_bounds__(256) conv2_fb_k(const float* __restrict__ h1,
                                                  const float* __restrict__ w,
                                                  const float* __restrict__ bias,
                                                  float* __restrict__ ft,
                                                  float* __restrict__ ftT) {
  __shared__ float ht[16][5][152];
  __shared__ float tile[32][51];
  int b = blockIdx.x / 50;
  int py = blockIdx.x % 50;
  int t = threadIdx.x;
  int lane = t & 63;
  int ob = RFL(t >> 6) * 8;
  int px = lane;
  int pxc = min(px, 49);
  int iy0 = py * 3 - 2;
  float acc[8];
#pragma unroll
  for (int u = 0; u < 8; ++u) acc[u] = 0.f;
  for (int ch = 0; ch < 4; ++ch) {
    __syncthreads();
    for (int e = t; e < 12160; e += 256) {
      int c = e / 760;
      int rest = e % 760;
      int r = rest / 152;
      int col = rest % 152;
      int iy = iy0 + r;
      int ix = col - 2;
      float v = 0.f;
      if (iy >= 0 && iy < 150 && ix >= 0 && ix < 150)
        v = h1[((size_t)(b * 64 + ch * 16 + c) * 150 + iy) * 150 + ix];
      ht[c][r][col] = v;
    }
    __syncthreads();
    for (int c = 0; c < 16; ++c) {
#pragma unroll
      for (int ky = 0; ky < 5; ++ky)
#pragma unroll
        for (int kx = 0; kx < 5; ++kx) {
          float xv = ht[c][ky][pxc * 3 + kx];
#pragma unroll
          for (int u = 0; u < 8; ++u)
            acc[u] += xv * w[(ob + u) * 1600 + (ch * 16 + c) * 25 + ky * 5 + kx];
        }
    }
  }
  if (px < 50) {
#pragma unroll
    for (int u = 0; u < 8; ++u)
      tile[ob + u][px] = fmaxf(acc[u] + bias[ob + u], 0.f);
  }
  __syncthreads();
  for (int e = t; e < 1600; e += 256) {
    int o = e / 50, p = e % 50;
    ft[(size_t)(b * 32 + o) * 2500 + py * 50 + p] = tile[o][p];
  }
  for (int e = t; e < 1600; e += 256) {
    int p = e >> 5, o = e & 31;
    ftT[((size_t)b * 2500 + py * 50 + p) * 32 + o] = tile[o][p];
  }
}

__global__ void __launch_bounds__(256) hg_gram_fb_k(const float* __restrict__ ftT,
                                                    float* __restrict__ gramP) {
  __shared__ float sl[50][32];
  int b = blockIdx.x, ch = blockIdx.y;   // ch 0..49
  const float* S = ftT + (size_t)b * 80000 + ch * 1600;
  int t = threadIdx.x;
  for (int e = t; e < 400; e += 256)
    ((float4*)sl)[e] = ((const float4*)S)[e];
  __syncthreads();
  int i = t >> 3, j0 = (t & 7) * 4;
  float4 a = make_float4(0.f, 0.f, 0.f, 0.f);
  for (int p = 0; p < 50; ++p) {
    float ai = sl[p][i];
    float4 bj = *(const float4*)&sl[p][j0];
    a.x += ai * bj.x; a.y += ai * bj.y; a.z += ai * bj.z; a.w += ai * bj.w;
  }
  *(float4*)(gramP + ((size_t)(b * 50 + ch)) * 1024 + t * 4) = a;
}

// ---------------- feature branch: qkv with enc fused (grid (8,3))
__global__ void __launch_bounds__(512) fk_qkv(const float* __restrict__ xf,
                                              const float* __restrict__ ew, const float* __restrict__ eb,
                                              const float* __restrict__ wq, const float* __restrict__ bq,
                                              const float* __restrict__ wk, const float* __restrict__ bk,
                                              const float* __restrict__ wv, const float* __restrict__ bv,
                                              float* __restrict__ qkv) {
  __shared__ float fs[512];
  int b = blockIdx.x, m = blockIdx.y, j = threadIdx.x;
  const float* W = (m == 0) ? wq : (m == 1) ? wk : wv;
  const float* B = (m == 0) ? bq : (m == 1) ? bk : bv;
  float fe = eb[j];
  for (int c = 0; c < 36; ++c) fe += xf[b * 36 + c] * ew[c * 512 + j];
  fs[j] = fmaxf(fe, 0.f);
  __syncthreads();
  float acc = B[j];
  for (int c = 0; c < 512; ++c) acc += fs[c] * W[(size_t)c * 512 + j];
  qkv[(m * 8 + b) * 512 + j] = acc;
}

// ---------------- attention scores + softmax + AV (per-b block)
__global__ void __launch_bounds__(512) fk_att(const float* __restrict__ qkv,
                                              float* __restrict__ aog) {
  __shared__ float att[2][8];
  int b = blockIdx.x, t = threadIdx.x;
  const float* q = qkv;
  const float* kk = qkv + 4096;
  const float* v = qkv + 8192;
  {
    int g = t >> 5, l = t & 31;
    int h = g >> 3, c = g & 7;
    const float* qb = q + b * 512 + h * 256;
    const float* kc = kk + c * 512 + h * 256;
    float s = 0.f;
    for (int d = l; d < 256; d += 32) s += qb[d] * kc[d];
#pragma unroll
    for (int m = 16; m >= 1; m >>= 1) s += __shfl_xor(s, m);
    if (l == 0) att[h][c] = s * (1.f / 16.f);
  }
  __syncthreads();
  if (t < 2) {
    int h = t;
    float mx = -1e30f;
#pragma unroll
    for (int c = 0; c < 8; ++c) mx = fmaxf(mx, att[h][c]);
    float e[8], s = 0.f;
#pragma unroll
    for (int c = 0; c < 8; ++c) { e[c] = expf(att[h][c] - mx); s += e[c]; }
#pragma unroll
    for (int c = 0; c < 8; ++c) att[h][c] = e[c] / s;
  }
  __syncthreads();
  {
    int j = t, h = j >> 8;
    float acc = 0.f;
#pragma unroll
    for (int c = 0; c < 8; ++c) acc += att[h][c] * v[c * 512 + j];
    aog[b * 512 + j] = acc;
  }
}

// ---------------- output projection: grid (8,2), 256 j columns per block
__global__ void __launch_bounds__(256) fk_wo(const float* __restrict__ aog,
                                             const float* __restrict__ wo,
                                             const float* __restrict__ bo,
                                             float* __restrict__ osg) {
  __shared__ float aos[512];
  int b = blockIdx.x, half = blockIdx.y, t = threadIdx.x;
  aos[t] = aog[b * 512 + t];
  aos[t + 256] = aog[b * 512 + t + 256];
  __syncthreads();
  int j = half * 256 + t;
  float acc = bo[j];
  for (int c = 0; c < 512; ++c) acc += aos[c] * wo[(size_t)c * 512 + j];
  osg[b * 512 + j] = acc;
}

// ---------------- decoder: one block covers all 8 samples
__global__ void __launch_bounds__(256) fk_dec(const float* __restrict__ osg,
                                              const float* __restrict__ dw,
                                              const float* __restrict__ db,
                                              float* __restrict__ f2) {
  int t = threadIdx.x;
  int b = t >> 5, j = t & 31;
  float acc = db[j];
  for (int c = 0; c < 512; ++c) acc += osg[b * 512 + c] * dw[c * 32 + j];
  f2[t] = fmaxf(acc, 0.f);
}

// ---------------- G combine: sum 50 partials, distances, top-5, normalize
__global__ void __launch_bounds__(256) hg_G2_k(const float* __restrict__ gramP,
                                               float* __restrict__ Gout) {
  int b = blockIdx.x;
  __shared__ float gram[32][32];
  __shared__ float d[32][32];
  __shared__ float avg[32];
  __shared__ float Hm[32][32];
  __shared__ float Hn[32][32];
  __shared__ float DE[32];
  __shared__ float dvi[32];
  int t = threadIdx.x;
  {
    float4 s = make_float4(0.f, 0.f, 0.f, 0.f);
    for (int ch = 0; ch < 50; ++ch) {
      float4 v = *(const float4*)(gramP + ((size_t)(b * 50 + ch)) * 1024 + t * 4);
      s.x += v.x; s.y += v.y; s.z += v.z; s.w += v.w;
    }
    *(float4*)(&gram[0][0] + t * 4) = s;
  }
  __syncthreads();
  for (int e = t; e < 1024; e += 256) {
    int i = e >> 5, j = e & 31;
    float d2 = gram[i][i] + gram[j][j] - 2.f * gram[i][j];
    float dd = sqrtf(fmaxf(d2, 0.f));
    if (i == j) dd = 0.f;
    d[i][j] = dd;
  }
  __syncthreads();
  if (t < 32) {
    float s = 0.f;
    for (int j = 0; j < 32; ++j) s += d[t][j];
    avg[t] = s * (1.f / 32.f);
  }
  for (int e = t; e < 1024; e += 256) Hm[e >> 5][e & 31] = 0.f;
  __syncthreads();
  if (t < 32) {
    unsigned picked = 0;
    float a = avg[t];
    float inv = 1.f / (a * a);
    for (int s = 0; s < 5; ++s) {
      float best = 1e30f;
      int bi = 0;
      for (int j = 0; j < 32; ++j) {
        if (picked & (1u << j)) continue;
        float dv = d[t][j];
        if (dv < best) { best = dv; bi = j; }
      }
      picked |= 1u << bi;
      Hm[bi][t] = expf(-best * best * inv);
    }
  }
  __syncthreads();
  if (t < 32) {
    float se = 0.f, sv = 0.f;
    for (int r = 0; r < 32; ++r) se += Hm[r][t];
    for (int c = 0; c < 32; ++c) sv += Hm[t][c];
    DE[t] = se;
    dvi[t] = 1.f / sqrtf(sv);
  }
  __syncthreads();
  for (int e = t; e < 1024; e += 256) {
    int i = e >> 5, j = e & 31;
    Hn[i][j] = Hm[i][j] * (1.f / DE[j]);
  }
  __syncthreads();
  for (int e = t; e < 1024; e += 256) {
    int i = e >> 5, j = e & 31;
    float acc = 0.f;
#pragma unroll
    for (int c = 0; c < 32; ++c) acc += Hn[i][c] * Hm[j][c];
    Gout[(size_t)b * 1024 + e] = dvi[i] * acc * dvi[j];
  }
}

// ---------------- t1 partials: ft[256,2500] @ w1[2500,512], 64 rowgroups x 16 k-chunks
__global__ void __launch_bounds__(512) hg_mm1_k(const float* __restrict__ ft,
                                                const float* __restrict__ w1,
                                                float* __restrict__ part) {
  int rg = blockIdx.x;   // 0..63 (4 rows each)
  int ch = blockIdx.y;   // 0..15
  int j = threadIdx.x;
  int r0 = rg * 4;
  int c0 = ch * 156 + min(ch, 4);
  int cn = 156 + (ch < 4 ? 1 : 0);
  float acc[4];
#pragma unroll
  for (int r = 0; r < 4; ++r) acc[r] = 0.f;
#pragma unroll 4
  for (int c = c0; c < c0 + cn; ++c) {
    float wv = w1[(size_t)c * 512 + j];
#pragma unroll
    for (int r = 0; r < 4; ++r)
      acc[r] += ft[(size_t)(r0 + r) * 2500 + c] * wv;  // uniform -> s_load
  }
#pragma unroll
  for (int r = 0; r < 4; ++r)
    part[(size_t)ch * 131072 + (r0 + r) * 512 + j] = acc[r];
}

__global__ void __launch_bounds__(256) mm1_comb_k(const float* __restrict__ part,
                                                  const float* __restrict__ b1,
                                                  float* __restrict__ t1) {
  int idx = blockIdx.x * 256 + threadIdx.x;
  if (idx >= 131072) return;
  float s = b1[idx & 511];
#pragma unroll
  for (int ch = 0; ch < 16; ++ch) s += part[(size_t)ch * 131072 + idx];
  t1[idx] = s;
}

// ---------------- tail part 1: z rows + t2 rows, grid (8,4) = 8 rows per block
__global__ void __launch_bounds__(512) tailz_k(const float* __restrict__ G,
                                               const float* __restrict__ t1,
                                               const float* __restrict__ w2,
                                               const float* __restrict__ b2,
                                               float* __restrict__ t2g) {
  int b = blockIdx.x, qd = blockIdx.y;
  int i0 = qd * 8;
  __shared__ float zs[8][512];
  int t = threadIdx.x;
  const float* Gb = G + b * 1024;
  const float* t1b = t1 + b * 16384;
  {
    int j = t;
    float acc[8];
#pragma unroll
    for (int i = 0; i < 8; ++i) acc[i] = 0.f;
    for (int c = 0; c < 32; ++c) {
      float tv = t1b[c * 512 + j];
#pragma unroll
      for (int i = 0; i < 8; ++i) acc[i] += Gb[(i0 + i) * 32 + c] * tv;  // uniform -> s_load
    }
#pragma unroll
    for (int i = 0; i < 8; ++i) zs[i][j] = fmaxf(acc[i], 0.f);
  }
  __syncthreads();
  if (t < 256) {
    int i = t >> 5, jj = t & 31;
    float acc = b2[jj];
    for (int c = 0; c < 512; ++c) acc += zs[i][c] * w2[c * 32 + jj];
    t2g[b * 1024 + (i0 + i) * 32 + jj] = acc;
  }
}

// ---------------- tail part 2: colmean via gcol + f2 + head (8 blocks)
__global__ void __launch_bounds__(256) head2_k(const float* __restrict__ G,
                                               const float* __restrict__ t2g,
                                               const float* __restrict__ f2,
                                               const float* __restrict__ hw,
                                               const float* __restrict__ hb,
                                               float* __restrict__ dout) {
  int b = blockIdx.x, t = threadIdx.x;
  __shared__ float t2s[32][32];
  __shared__ float gcol[32];
  __shared__ float ov[32];
  for (int e = t; e < 1024; e += 256)
    ((float*)t2s)[e] = t2g[b * 1024 + e];
  if (t < 32) {
    float s = 0.f;
    for (int i = 0; i < 32; ++i) s += G[b * 1024 + i * 32 + t];
    gcol[t] = s;
  }
  __syncthreads();
  if (t < 32) {
    int j = t;
    float s = 0.f;
#pragma unroll
    for (int c = 0; c < 32; ++c) s += gcol[c] * t2s[c][j];
    float fv = f2[b * 32 + j];
    ov[j] = s * (1.f / 32.f) + fv;
    dout[8000 + b * 32 + j] = fv;      // tuple output 1: f
  }
  __syncthreads();
  for (int j = t; j < 1000; j += 256) {
    float a = hb[j];
#pragma unroll
    for (int c = 0; c < 32; ++c) a += ov[c] * hw[c * 1000 + j];
    dout[b * 1000 + j] = a;            // tuple output 0: logits
  }
}

extern "C" void kernel_launch(void* const* d_in, const int* in_sizes, int n_in,
                              void* d_out, int out_size, void* d_ws, size_t ws_size,
                              hipStream_t stream) {
  const float* x     = (const float*)d_in[0];
  const float* xf    = (const float*)d_in[1];
  const float* c1w   = (const float*)d_in[2];
  const float* c1b   = (const float*)d_in[3];
  const float* c2w   = (const float*)d_in[4];
  const float* c2b   = (const float*)d_in[5];
  const float* enc_w = (const float*)d_in[6];
  const float* enc_b = (const float*)d_in[7];
  const float* wq    = (const float*)d_in[8];
  const float* bq    = (const float*)d_in[9];
  const float* wk    = (const float*)d_in[10];
  const float* bk    = (const float*)d_in[11];
  const float* wv    = (const float*)d_in[12];
  const float* bv    = (const float*)d_in[13];
  const float* wo    = (const float*)d_in[14];
  const float* bo    = (const float*)d_in[15];
  const float* dec_w = (const float*)d_in[16];
  const float* dec_b = (const float*)d_in[17];
  const float* w1    = (const float*)d_in[18];
  const float* b1    = (const float*)d_in[19];
  const float* w2    = (const float*)d_in[20];
  const float* b2    = (const float*)d_in[21];
  const float* hw    = (const float*)d_in[22];
  const float* hb    = (const float*)d_in[23];
  float* out = (float*)d_out;

  float* ws = (float*)d_ws;
  // layout (floats):
  float* h1   = ws;                  // [0, 11,520,000)  dead after conv2p
  float* ftb  = ws + 11520000;       // 640,000
  float* ftT  = ws + 12160000;       // 640,000 (fallback path only)
  float* qkv  = ws + 12800000;       // 12,288
  float* aog  = ws + 12812288;       // 4,096
  float* f2   = ws + 12816384;       // 256
  float* osg  = ws + 12816640;       // 4,096
  float* G    = ws + 12820736;       // 8,192  -> 12,828,928
  float* part2= ws + 12828928;       // 5,120,000 -> 17,948,928 (71.8 MB)
  // overlays on ftb region (dead until comb2g writes it; convs done by then):
  float* c1wT = ws + 11520000;       // 4,800
  float* c2wT = ws + 11524800;       // 51,200
  // overlays on dead h1 region (used only after conv2p completes):
  float* part = ws;                  // 2,097,152
  float* t1   = ws + 2097152;        // 131,072 -> 2,228,224
  float* gramP= ws + 2228224;        // 409,600 -> 2,637,824
  float* t2g  = ws + 2637824;        // 8,192   -> 2,646,016

  bool big = ws_size >= (size_t)17948928 * 4;

  wT_k<<<219, 256, 0, stream>>>(c1w, c2w, c1wT, c2wT);
  conv1_k<<<8 * 75, 512, 0, stream>>>(x, c1wT, c1b, h1);
  if (big) {
    conv2p_k<<<8 * 25 * 8, 512, 0, stream>>>(h1, c2wT, part2);
    dim3 gc(8, 50);
    comb2g_k<<<gc, 256, 0, stream>>>(part2, c2b, ftb, gramP);
  } else {
    conv2_fb_k<<<8 * 50, 256, 0, stream>>>(h1, c2w, c2b, ftb, ftT);
    dim3 gg(8, 50);
    hg_gram_fb_k<<<gg, 256, 0, stream>>>(ftT, gramP);
  }

  dim3 gq(8, 3);
  fk_qkv<<<gq, 512, 0, stream>>>(xf, enc_w, enc_b, wq, bq, wk, bk, wv, bv, qkv);
  fk_att<<<8, 512, 0, stream>>>(qkv, aog);
  dim3 gw(8, 2);
  fk_wo<<<gw, 256, 0, stream>>>(aog, wo, bo, osg);
  fk_dec<<<1, 256, 0, stream>>>(osg, dec_w, dec_b, f2);

  hg_G2_k<<<8, 256, 0, stream>>>(gramP, G);
  dim3 gm(64, 16);
  hg_mm1_k<<<gm, 512, 0, stream>>>(ftb, w1, part);
  mm1_comb_k<<<512, 256, 0, stream>>>(part, b1, t1);
  dim3 gz(8, 4);
  tailz_k<<<gz, 512, 0, stream>>>(G, t1, w2, b2, t2g);
  head2_k<<<8, 256, 0, stream>>>(G, t2g, f2, hw, hb, out);
}

// Round 23
// 221.998 us; speedup vs baseline: 1.0405x; 1.0405x over previous
//
#include <hip/hip_runtime.h>
#include <hip/hip_bf16.h>

#define RFL(x) __builtin_amdgcn_readfirstlane(x)

// ---------------- weight transpose: c1wT[k][64], c2wT[k][32]
__global__ void __launch_bounds__(256) wT_k(const float* __restrict__ c1w,
                                            const float* __restrict__ c2w,
                                            float* __restrict__ c1wT,
                                            float* __restrict__ c2wT) {
  int idx = blockIdx.x * 256 + threadIdx.x;
  if (idx < 4800) {
    int o = idx / 75, k = idx % 75;
    c1wT[k * 64 + o] = c1w[idx];
  } else if (idx < 56000) {
    int j = idx - 4800;
    int o = j / 1600, k = j % 1600;
    c2wT[k * 32 + o] = c2w[j];
  }
}

// ---------------- conv1 (R16-best): block = (b, row-pair), 512 thr, 8 waves = (row, o-quarter 16o)
__global__ void __launch_bounds__(512) conv1_k(const float* __restrict__ x,
                                               const float* __restrict__ wT,
                                               const float* __restrict__ bias,
                                               float* __restrict__ out) {
  __shared__ float xt[3][8][456];   // rows iy0..iy0+7, col = ix+2
  int b = blockIdx.x / 75;
  int py2 = blockIdx.x % 75;        // output rows 2*py2, 2*py2+1
  int t = threadIdx.x;
  int iy0 = py2 * 6 - 2;
  if (t < 456) {
    int ix = t - 2;
    bool cok = (ix >= 0) && (ix < 448);
#pragma unroll
    for (int c = 0; c < 3; ++c) {
      const float* xp = x + (size_t)(b * 3 + (2 - c)) * 200704;
#pragma unroll
      for (int r = 0; r < 8; ++r) {
        int iy = iy0 + r;
        bool rok = (iy >= 0) && (iy < 448);
        xt[c][r][t] = (rok && cok) ? xp[(size_t)iy * 448 + ix] : 0.f;
      }
    }
  }
  __syncthreads();
  int lane = t & 63;
  int w = RFL(t >> 6);              // 0..7
  int pl = w >> 2;                  // row-local 0/1
  int ob = (w & 3) * 16;            // o base 0/16/32/48
  int py = py2 * 2 + pl;
  int rbase = pl * 3;
  for (int sub = 0; sub < 3; ++sub) {
    int px = sub * 64 + lane;
    int pxc = min(px, 149);
    float acc[16];
#pragma unroll
    for (int u = 0; u < 16; ++u) acc[u] = 0.f;
    for (int c = 0; c < 3; ++c)
#pragma unroll
      for (int ky = 0; ky < 5; ++ky)
#pragma unroll
        for (int kx = 0; kx < 5; ++kx) {
          float xv = xt[c][rbase + ky][pxc * 3 + kx];
          const float* wr = wT + (c * 25 + ky * 5 + kx) * 64 + ob;  // uniform -> s_load
#pragma unroll
          for (int u = 0; u < 16; ++u) acc[u] += xv * wr[u];
        }
    if (px < 150) {
#pragma unroll
      for (int u = 0; u < 16; ++u)
        out[(size_t)(b * 64 + ob + u) * 22500 + py * 150 + px] =
            fmaxf(acc[u] + bias[ob + u], 0.f);
    }
  }
}

// ---------------- conv2 split-K partial (R16 frozen): block = (b, py-pair, ch), 512 thr,
// 8 waves = (row-local x 4 o-groups of 8 o). LDS 38.9KB.
__global__ void __launch_bounds__(512) conv2p_k(const float* __restrict__ h1,
                                                const float* __restrict__ wT,
                                                float* __restrict__ part2) {
  __shared__ float ht[8][8][152];   // rows iy0..iy0+7
  int blk = blockIdx.x;
  int ch = blk & 7;
  int bpy = blk >> 3;
  int b = bpy / 25;
  int py2 = bpy % 25;               // output rows 2*py2, 2*py2+1
  int t = threadIdx.x;
  int iy0 = py2 * 6 - 2;
  const float* hbase = h1 + (size_t)(b * 64 + ch * 8) * 22500;
  {
    int sub = t >> 7;               // 0..3
    int col = t & 127;
    bool cok = col >= 2;
#pragma unroll
    for (int i = 0; i < 16; ++i) {
      int c = sub * 2 + (i >> 3);   // i>>3 compile-time
      const int r = i & 7;
      int iy = iy0 + r;
      bool ok = (iy >= 0) & (iy < 150) & cok;
      float v = ok ? hbase[c * 22500 + iy * 150 + (col - 2)] : 0.f;
      ht[c][r][col] = v;
    }
#pragma unroll
    for (int it = 0; it < 3; ++it) {
      int e = it * 512 + t;
      int pair = (e * 2731) >> 16;       // e/24
      int col2 = e - pair * 24;
      int c = pair >> 3, r = pair & 7;
      int iy = iy0 + r;
      bool ok = (iy >= 0) & (iy < 150);
      float v = ok ? hbase[c * 22500 + iy * 150 + 126 + col2] : 0.f;
      ht[c][r][128 + col2] = v;
    }
  }
  __syncthreads();
  int lane = t & 63;
  int w = RFL(t >> 6);              // 0..7
  int pl = w >> 2;                  // row-local 0/1
  int ob = (w & 3) * 8;             // o base 0/8/16/24
  int py = py2 * 2 + pl;
  int rbase = pl * 3;
  int pxc = min(lane, 49);
  float acc[8];
#pragma unroll
  for (int u = 0; u < 8; ++u) acc[u] = 0.f;
#pragma unroll
  for (int c = 0; c < 8; ++c)
#pragma unroll
    for (int ky = 0; ky < 5; ++ky)
#pragma unroll
      for (int kx = 0; kx < 5; ++kx) {
        float xv = ht[c][rbase + ky][pxc * 3 + kx];
        const float* wr = wT + ((ch * 8 + c) * 25 + ky * 5 + kx) * 32 + ob;  // s_load
#pragma unroll
        for (int u = 0; u < 8; ++u) acc[u] += xv * wr[u];
      }
  if (lane < 50) {
#pragma unroll
    for (int u = 0; u < 8; ++u)
      part2[((size_t)ch * 256 + b * 32 + ob + u) * 2500 + py * 50 + lane] = acc[u];
  }
}

// ---------------- conv2 combine + gram partial: grid (8,25) = 100 p per block (R11)
__global__ void __launch_bounds__(256) comb2g_k(const float* __restrict__ part2,
                                                const float* __restrict__ bias,
                                                float* __restrict__ ft,
                                                float* __restrict__ gramP) {
  __shared__ float tile[32][102];
  __shared__ float tileT[100][36];
  int b = blockIdx.x, pc = blockIdx.y;
  int p0 = pc * 100;
  int t = threadIdx.x;
  for (int e = t; e < 3200; e += 256) {
    int o = e / 100, p = e % 100;
    float s = bias[o];
#pragma unroll
    for (int ch = 0; ch < 8; ++ch)
      s += part2[((size_t)ch * 256 + b * 32 + o) * 2500 + p0 + p];
    float v = fmaxf(s, 0.f);
    tile[o][p] = v;
    tileT[p][o] = v;
  }
  __syncthreads();
  for (int e = t; e < 3200; e += 256) {
    int o = e / 100, p = e % 100;
    ft[(size_t)(b * 32 + o) * 2500 + p0 + p] = tile[o][p];
  }
  int i = t >> 3, j0 = (t & 7) * 4;
  float4 a = make_float4(0.f, 0.f, 0.f, 0.f);
  for (int p = 0; p < 100; ++p) {
    float ai = tileT[p][i];
    float4 bj = *(const float4*)&tileT[p][j0];
    a.x += ai * bj.x; a.y += ai * bj.y; a.z += ai * bj.z; a.w += ai * bj.w;
  }
  *(float4*)(gramP + ((size_t)(b * 25 + pc)) * 1024 + t * 4) = a;
}

// ---------------- conv2 fallback (monolithic) + gram — used if ws too small
__global__ void __launch_bounds__(256) conv2_fb_k(const float* __restrict__ h1,
                                                  const float* __restrict__ w,
                                                  const float* __restrict__ bias,
                                                  float* __restrict__ ft,
                                                  float* __restrict__ ftT) {
  __shared__ float ht[16][5][152];
  __shared__ float tile[32][51];
  int b = blockIdx.x / 50;
  int py = blockIdx.x % 50;
  int t = threadIdx.x;
  int lane = t & 63;
  int ob = RFL(t >> 6) * 8;
  int px = lane;
  int pxc = min(px, 49);
  int iy0 = py * 3 - 2;
  float acc[8];
#pragma unroll
  for (int u = 0; u < 8; ++u) acc[u] = 0.f;
  for (int ch = 0; ch < 4; ++ch) {
    __syncthreads();
    for (int e = t; e < 12160; e += 256) {
      int c = e / 760;
      int rest = e % 760;
      int r = rest / 152;
      int col = rest % 152;
      int iy = iy0 + r;
      int ix = col - 2;
      float v = 0.f;
      if (iy >= 0 && iy < 150 && ix >= 0 && ix < 150)
        v = h1[((size_t)(b * 64 + ch * 16 + c) * 150 + iy) * 150 + ix];
      ht[c][r][col] = v;
    }
    __syncthreads();
    for (int c = 0; c < 16; ++c) {
#pragma unroll
      for (int ky = 0; ky < 5; ++ky)
#pragma unroll
        for (int kx = 0; kx < 5; ++kx) {
          float xv = ht[c][ky][pxc * 3 + kx];
#pragma unroll
          for (int u = 0; u < 8; ++u)
            acc[u] += xv * w[(ob + u) * 1600 + (ch * 16 + c) * 25 + ky * 5 + kx];
        }
    }
  }
  if (px < 50) {
#pragma unroll
    for (int u = 0; u < 8; ++u)
      tile[ob + u][px] = fmaxf(acc[u] + bias[ob + u], 0.f);
  }
  __syncthreads();
  for (int e = t; e < 1600; e += 256) {
    int o = e / 50, p = e % 50;
    ft[(size_t)(b * 32 + o) * 2500 + py * 50 + p] = tile[o][p];
  }
  for (int e = t; e < 1600; e += 256) {
    int p = e >> 5, o = e & 31;
    ftT[((size_t)b * 2500 + py * 50 + p) * 32 + o] = tile[o][p];
  }
}

__global__ void __launch_bounds__(256) hg_gram_fb_k(const float* __restrict__ ftT,
                                                    float* __restrict__ gramP) {
  __shared__ float sl[100][32];
  int b = blockIdx.x, ch = blockIdx.y;
  const float* S = ftT + (size_t)b * 80000 + ch * 3200;
  int t = threadIdx.x;
  for (int e = t; e < 800; e += 256)
    ((float4*)sl)[e] = ((const float4*)S)[e];
  __syncthreads();
  int i = t >> 3, j0 = (t & 7) * 4;
  float4 a = make_float4(0.f, 0.f, 0.f, 0.f);
  for (int p = 0; p < 100; ++p) {
    float ai = sl[p][i];
    float4 bj = *(const float4*)&sl[p][j0];
    a.x += ai * bj.x; a.y += ai * bj.y; a.z += ai * bj.z; a.w += ai * bj.w;
  }
  *(float4*)(gramP + ((size_t)(b * 25 + ch)) * 1024 + t * 4) = a;
}

// ---------------- feature branch: enc (8 blocks)
__global__ void __launch_bounds__(512) fk_enc(const float* __restrict__ xf,
                                              const float* __restrict__ ew,
                                              const float* __restrict__ eb,
                                              float* __restrict__ f) {
  int b = blockIdx.x, j = threadIdx.x;
  float acc = eb[j];
  for (int c = 0; c < 36; ++c) acc += xf[b * 36 + c] * ew[c * 512 + j];
  f[b * 512 + j] = fmaxf(acc, 0.f);
}

// ---------------- feature branch: qkv, grid (8,3)
__global__ void __launch_bounds__(512) fk_qkv(const float* __restrict__ f,
                                              const float* __restrict__ wq, const float* __restrict__ bq,
                                              const float* __restrict__ wk, const float* __restrict__ bk,
                                              const float* __restrict__ wv, const float* __restrict__ bv,
                                              float* __restrict__ qkv) {
  __shared__ float fs[512];
  int b = blockIdx.x, m = blockIdx.y, j = threadIdx.x;
  const float* W = (m == 0) ? wq : (m == 1) ? wk : wv;
  const float* B = (m == 0) ? bq : (m == 1) ? bk : bv;
  fs[j] = f[b * 512 + j];
  __syncthreads();
  float acc = B[j];
  for (int c = 0; c < 512; ++c) acc += fs[c] * W[(size_t)c * 512 + j];
  qkv[(m * 8 + b) * 512 + j] = acc;
}

// ---------------- fused attention + output proj + decoder (per-b block)
__global__ void __launch_bounds__(512) fk_ao_k(const float* __restrict__ qkv,
                                               const float* __restrict__ wo, const float* __restrict__ bo,
                                               const float* __restrict__ dw, const float* __restrict__ db,
                                               float* __restrict__ f2) {
  __shared__ float att[2][8];
  __shared__ float aos[512];
  __shared__ float os[512];
  int b = blockIdx.x, t = threadIdx.x;
  const float* q = qkv;
  const float* kk = qkv + 4096;
  const float* v = qkv + 8192;
  {
    int g = t >> 5, l = t & 31;
    int h = g >> 3, c = g & 7;
    const float* qb = q + b * 512 + h * 256;
    const float* kc = kk + c * 512 + h * 256;
    float s = 0.f;
    for (int d = l; d < 256; d += 32) s += qb[d] * kc[d];
#pragma unroll
    for (int m = 16; m >= 1; m >>= 1) s += __shfl_xor(s, m);
    if (l == 0) att[h][c] = s * (1.f / 16.f);
  }
  __syncthreads();
  if (t < 2) {
    int h = t;
    float mx = -1e30f;
#pragma unroll
    for (int c = 0; c < 8; ++c) mx = fmaxf(mx, att[h][c]);
    float e[8], s = 0.f;
#pragma unroll
    for (int c = 0; c < 8; ++c) { e[c] = expf(att[h][c] - mx); s += e[c]; }
#pragma unroll
    for (int c = 0; c < 8; ++c) att[h][c] = e[c] / s;
  }
  __syncthreads();
  {
    int j = t, h = j >> 8;
    float acc = 0.f;
#pragma unroll
    for (int c = 0; c < 8; ++c) acc += att[h][c] * v[c * 512 + j];
    aos[j] = acc;
  }
  __syncthreads();
  {
    int j = t;
    float acc = bo[j];
    for (int c = 0; c < 512; ++c) acc += aos[c] * wo[(size_t)c * 512 + j];
    os[j] = acc;
  }
  __syncthreads();
  if (t < 32) {
    float a2 = db[t];
    for (int c = 0; c < 512; ++c) a2 += os[c] * dw[c * 32 + t];
    f2[b * 32 + t] = fmaxf(a2, 0.f);
  }
}

// ---------------- G combine: sum partials, distances, top-5, normalize
__global__ void __launch_bounds__(256) hg_G2_k(const float* __restrict__ gramP,
                                               float* __restrict__ Gout) {
  int b = blockIdx.x;
  __shared__ float gram[32][32];
  __shared__ float d[32][32];
  __shared__ float avg[32];
  __shared__ float Hm[32][32];
  __shared__ float Hn[32][32];
  __shared__ float DE[32];
  __shared__ float dvi[32];
  int t = threadIdx.x;
  {
    float4 s = make_float4(0.f, 0.f, 0.f, 0.f);
    for (int ch = 0; ch < 25; ++ch) {
      float4 v = *(const float4*)(gramP + ((size_t)(b * 25 + ch)) * 1024 + t * 4);
      s.x += v.x; s.y += v.y; s.z += v.z; s.w += v.w;
    }
    *(float4*)(&gram[0][0] + t * 4) = s;
  }
  __syncthreads();
  for (int e = t; e < 1024; e += 256) {
    int i = e >> 5, j = e & 31;
    float d2 = gram[i][i] + gram[j][j] - 2.f * gram[i][j];
    float dd = sqrtf(fmaxf(d2, 0.f));
    if (i == j) dd = 0.f;
    d[i][j] = dd;
  }
  __syncthreads();
  if (t < 32) {
    float s = 0.f;
    for (int j = 0; j < 32; ++j) s += d[t][j];
    avg[t] = s * (1.f / 32.f);
  }
  for (int e = t; e < 1024; e += 256) Hm[e >> 5][e & 31] = 0.f;
  __syncthreads();
  if (t < 32) {
    unsigned picked = 0;
    float a = avg[t];
    float inv = 1.f / (a * a);
    for (int s = 0; s < 5; ++s) {
      float best = 1e30f;
      int bi = 0;
      for (int j = 0; j < 32; ++j) {
        if (picked & (1u << j)) continue;
        float dv = d[t][j];
        if (dv < best) { best = dv; bi = j; }
      }
      picked |= 1u << bi;
      Hm[bi][t] = expf(-best * best * inv);
    }
  }
  __syncthreads();
  if (t < 32) {
    float se = 0.f, sv = 0.f;
    for (int r = 0; r < 32; ++r) se += Hm[r][t];
    for (int c = 0; c < 32; ++c) sv += Hm[t][c];
    DE[t] = se;
    dvi[t] = 1.f / sqrtf(sv);
  }
  __syncthreads();
  for (int e = t; e < 1024; e += 256) {
    int i = e >> 5, j = e & 31;
    Hn[i][j] = Hm[i][j] * (1.f / DE[j]);
  }
  __syncthreads();
  for (int e = t; e < 1024; e += 256) {
    int i = e >> 5, j = e & 31;
    float acc = 0.f;
#pragma unroll
    for (int c = 0; c < 32; ++c) acc += Hn[i][c] * Hm[j][c];
    Gout[(size_t)b * 1024 + e] = dvi[i] * acc * dvi[j];
  }
}

// ---------------- t1 partials: ft[256,2500] @ w1[2500,512], 64 rowgroups x 16 k-chunks
__global__ void __launch_bounds__(512) hg_mm1_k(const float* __restrict__ ft,
                                                const float* __restrict__ w1,
                                                float* __restrict__ part) {
  int rg = blockIdx.x;   // 0..63 (4 rows each)
  int ch = blockIdx.y;   // 0..15
  int j = threadIdx.x;
  int r0 = rg * 4;
  int c0 = ch * 156 + min(ch, 4);
  int cn = 156 + (ch < 4 ? 1 : 0);
  float acc[4];
#pragma unroll
  for (int r = 0; r < 4; ++r) acc[r] = 0.f;
#pragma unroll 4
  for (int c = c0; c < c0 + cn; ++c) {
    float wv = w1[(size_t)c * 512 + j];
#pragma unroll
    for (int r = 0; r < 4; ++r)
      acc[r] += ft[(size_t)(r0 + r) * 2500 + c] * wv;  // uniform -> s_load
  }
#pragma unroll
  for (int r = 0; r < 4; ++r)
    part[(size_t)ch * 131072 + (r0 + r) * 512 + j] = acc[r];
}

__global__ void __launch_bounds__(256) mm1_comb_k(const float* __restrict__ part,
                                                  const float* __restrict__ b1,
                                                  float* __restrict__ t1) {
  int idx = blockIdx.x * 256 + threadIdx.x;
  if (idx >= 131072) return;
  float s = b1[idx & 511];
#pragma unroll
  for (int ch = 0; ch < 16; ++ch) s += part[(size_t)ch * 131072 + idx];
  t1[idx] = s;
}

// ---------------- tail part 1: z rows + t2 rows, grid (8,4) = 8 rows per block
__global__ void __launch_bounds__(512) tailz_k(const float* __restrict__ G,
                                               const float* __restrict__ t1,
                                               const float* __restrict__ w2,
                                               const float* __restrict__ b2,
                                               float* __restrict__ t2g) {
  int b = blockIdx.x, qd = blockIdx.y;
  int i0 = qd * 8;
  __shared__ float zs[8][512];
  int t = threadIdx.x;
  const float* Gb = G + b * 1024;
  const float* t1b = t1 + b * 16384;
  {
    int j = t;
    float acc[8];
#pragma unroll
    for (int i = 0; i < 8; ++i) acc[i] = 0.f;
    for (int c = 0; c < 32; ++c) {
      float tv = t1b[c * 512 + j];
#pragma unroll
      for (int i = 0; i < 8; ++i) acc[i] += Gb[(i0 + i) * 32 + c] * tv;  // uniform -> s_load
    }
#pragma unroll
    for (int i = 0; i < 8; ++i) zs[i][j] = fmaxf(acc[i], 0.f);
  }
  __syncthreads();
  if (t < 256) {
    int i = t >> 5, jj = t & 31;
    float acc = b2[jj];
    for (int c = 0; c < 512; ++c) acc += zs[i][c] * w2[c * 32 + jj];
    t2g[b * 1024 + (i0 + i) * 32 + jj] = acc;
  }
}

// ---------------- tail part 2: colmean via gcol + f2 + head (8 blocks)
__global__ void __launch_bounds__(256) head2_k(const float* __restrict__ G,
                                               const float* __restrict__ t2g,
                                               const float* __restrict__ f2,
                                               const float* __restrict__ hw,
                                               const float* __restrict__ hb,
                                               float* __restrict__ dout) {
  int b = blockIdx.x, t = threadIdx.x;
  __shared__ float t2s[32][32];
  __shared__ float gcol[32];
  __shared__ float ov[32];
  for (int e = t; e < 1024; e += 256)
    ((float*)t2s)[e] = t2g[b * 1024 + e];
  if (t < 32) {
    float s = 0.f;
    for (int i = 0; i < 32; ++i) s += G[b * 1024 + i * 32 + t];
    gcol[t] = s;
  }
  __syncthreads();
  if (t < 32) {
    int j = t;
    float s = 0.f;
#pragma unroll
    for (int c = 0; c < 32; ++c) s += gcol[c] * t2s[c][j];
    float fv = f2[b * 32 + j];
    ov[j] = s * (1.f / 32.f) + fv;
    dout[8000 + b * 32 + j] = fv;      // tuple output 1: f
  }
  __syncthreads();
  for (int j = t; j < 1000; j += 256) {
    float a = hb[j];
#pragma unroll
    for (int c = 0; c < 32; ++c) a += ov[c] * hw[c * 1000 + j];
    dout[b * 1000 + j] = a;            // tuple output 0: logits
  }
}

extern "C" void kernel_launch(void* const* d_in, const int* in_sizes, int n_in,
                              void* d_out, int out_size, void* d_ws, size_t ws_size,
                              hipStream_t stream) {
  const float* x     = (const float*)d_in[0];
  const float* xf    = (const float*)d_in[1];
  const float* c1w   = (const float*)d_in[2];
  const float* c1b   = (const float*)d_in[3];
  const float* c2w   = (const float*)d_in[4];
  const float* c2b   = (const float*)d_in[5];
  const float* enc_w = (const float*)d_in[6];
  const float* enc_b = (const float*)d_in[7];
  const float* wq    = (const float*)d_in[8];
  const float* bq    = (const float*)d_in[9];
  const float* wk    = (const float*)d_in[10];
  const float* bk    = (const float*)d_in[11];
  const float* wv    = (const float*)d_in[12];
  const float* bv    = (const float*)d_in[13];
  const float* wo    = (const float*)d_in[14];
  const float* bo    = (const float*)d_in[15];
  const float* dec_w = (const float*)d_in[16];
  const float* dec_b = (const float*)d_in[17];
  const float* w1    = (const float*)d_in[18];
  const float* b1    = (const float*)d_in[19];
  const float* w2    = (const float*)d_in[20];
  const float* b2    = (const float*)d_in[21];
  const float* hw    = (const float*)d_in[22];
  const float* hb    = (const float*)d_in[23];
  float* out = (float*)d_out;

  float* ws = (float*)d_ws;
  // layout (floats):
  float* h1   = ws;                  // [0, 11,520,000)  dead after conv2p
  float* ftb  = ws + 11520000;       // 640,000
  float* ftT  = ws + 12160000;       // 640,000 (fallback path only)
  float* qkv  = ws + 12800000;       // 12,288
  float* f    = ws + 12812288;       // 4,096
  float* f2   = ws + 12816384;       // 256
  float* G    = ws + 12816896;       // 8,192  -> 12,825,088
  float* part2= ws + 12825088;       // 5,120,000 -> 17,945,088 (71.8 MB)
  // overlays on ftb region (dead until comb2g writes it; convs done by then):
  float* c1wT = ws + 11520000;       // 4,800
  float* c2wT = ws + 11524800;       // 51,200
  // overlays on dead h1 region (used only after conv2p completes):
  float* part = ws;                  // 2,097,152
  float* t1   = ws + 2097152;        // 131,072 -> 2,228,224
  float* gramP= ws + 2228224;        // 204,800 -> 2,433,024
  float* t2g  = ws + 2433024;        // 8,192   -> 2,441,216

  bool big = ws_size >= (size_t)17945088 * 4;

  wT_k<<<219, 256, 0, stream>>>(c1w, c2w, c1wT, c2wT);
  conv1_k<<<8 * 75, 512, 0, stream>>>(x, c1wT, c1b, h1);
  if (big) {
    conv2p_k<<<8 * 25 * 8, 512, 0, stream>>>(h1, c2wT, part2);
    dim3 gc(8, 25);
    comb2g_k<<<gc, 256, 0, stream>>>(part2, c2b, ftb, gramP);
  } else {
    conv2_fb_k<<<8 * 50, 256, 0, stream>>>(h1, c2w, c2b, ftb, ftT);
    dim3 gg(8, 25);
    hg_gram_fb_k<<<gg, 256, 0, stream>>>(ftT, gramP);
  }

  fk_enc<<<8, 512, 0, stream>>>(xf, enc_w, enc_b, f);
  dim3 gq(8, 3);
  fk_qkv<<<gq, 512, 0, stream>>>(f, wq, bq, wk, bk, wv, bv, qkv);
  fk_ao_k<<<8, 512, 0, stream>>>(qkv, wo, bo, dec_w, dec_b, f2);

  hg_G2_k<<<8, 256, 0, stream>>>(gramP, G);
  dim3 gm(64, 16);
  hg_mm1_k<<<gm, 512, 0, stream>>>(ftb, w1, part);
  mm1_comb_k<<<512, 256, 0, stream>>>(part, b1, t1);
  dim3 gz(8, 4);
  tailz_k<<<gz, 512, 0, stream>>>(G, t1, w2, b2, t2g);
  head2_k<<<8, 256, 0, stream>>>(G, t2g, f2, hw, hb, out);
}